// Round 3
// baseline (1592.665 us; speedup 1.0000x reference)
//
#include <hip/hip_runtime.h>

#define Bn 20
#define Cn 395
#define Hn 10
#define Tn 8192
#define TP (Tn + 8)          // padded timesteps in the pre buffers (scan prefetch slack)
#define GIN 800              // 2*C + H
#define CP 400               // padded C
#define NL2E (-1.4426950408889634f)
#define KC (2.f * NL2E)      // the tanh pre-scale; scan carries cs = KC*c recurrently

// ---------------- Phase 0: build scaled, scan-ordered weight table ----------------------------
// wt[c][q]      = Wg[h][c]        * s_g   (q = h*4+g, x part)
// wt[c][40+q]   = Wg[h][C+H+c]    * s_g   (y part);  rows c>=395 are zero padding.
__global__ __launch_bounds__(256) void pclstm_wt(
    const float* __restrict__ Wf, const float* __restrict__ Wi,
    const float* __restrict__ Wu, const float* __restrict__ Wo,
    float* __restrict__ wt)
{
  int i = blockIdx.x * 256 + threadIdx.x;        // over CP*80
  if (i >= CP * 80) return;
  int c = i / 80;
  int q = i - c * 80;
  float v = 0.f;
  if (c < Cn) {
    int qq = (q < 40) ? q : q - 40;
    int h = qq >> 2;
    int g = qq & 3;
    const float* W = (g == 0) ? Wf : (g == 1) ? Wi : (g == 2) ? Wu : Wo;
    float s = (g == 2) ? 2.f * NL2E : NL2E;
    int col = (q < 40) ? c : (Cn + Hn + c);
    v = W[h * GIN + col] * s;
  }
  wt[i] = v;
}

// ---------------- Phase 1: partial pre, c-split in two halves ---------------------------------
// DS-pipe model: each uniform ds_read_b128 costs the CU's LDS pipe ~12-16 cyc regardless of
// broadcast. So each wave must stream as FEW weight reads per output as possible while the
// grid stays at 640 balanced blocks: 2 t-values per thread (weights amortized 2x) AND a
// c-split over blockIdx.z (each wave streams only half the table). Halves summed in the scan.
#define SC 40                 // c-rows per LDS stage (multiple of 8 keeps ring index static)
#define CHALF 200             // c-rows per z-half
#define NST (CHALF / SC)      // 5

__global__ __launch_bounds__(256, 3) void pclstm_pre(
    const float* __restrict__ x, const float* __restrict__ y,
    const float* __restrict__ wt,
    float* __restrict__ preA, float* __restrict__ preB)
{
  __shared__ float4 wls[SC * 20];                // 40 rows x 80 floats = 12.8 KB

  const int tid = threadIdx.x;
  const int b = blockIdx.y;
  const int ch = blockIdx.z;
  const int c0 = ch * CHALF;
  const int t0 = blockIdx.x * 512 + tid;
  const int t1 = t0 + 256;

  const float* xb0 = x + (size_t)b * Cn * Tn + t0;
  const float* xb1 = xb0 + 256;
  const float* yb0 = y + (size_t)b * Cn * Tn + ((t0 > 0) ? t0 - 1 : 0);
  const float* yb1 = y + (size_t)b * Cn * Tn + (t1 - 1);
  const float ym0 = (t0 > 0) ? 1.f : 0.f;        // t1 >= 256, never needs masking

  float acc0[40], acc1[40];
#pragma unroll
  for (int q = 0; q < 40; ++q) { acc0[q] = 0.f; acc1[q] = 0.f; }

  // 8-deep register ring prefetch of x / y_prev for both t-slices (rows c0..c0+7, all < Cn)
  float xr0[8], yr0[8], xr1[8], yr1[8];
#pragma unroll
  for (int d = 0; d < 8; ++d) {
    xr0[d] = xb0[(size_t)(c0 + d) * Tn];
    yr0[d] = ym0 * yb0[(size_t)(c0 + d) * Tn];
    xr1[d] = xb1[(size_t)(c0 + d) * Tn];
    yr1[d] = yb1[(size_t)(c0 + d) * Tn];
  }

  const float4* wt4 = reinterpret_cast<const float4*>(wt);

  for (int s = 0; s < NST; ++s) {                // rolled: keeps code inside L1I
    __syncthreads();                             // previous stage fully consumed
#pragma unroll
    for (int i = 0; i < 4; ++i) {                // 800 float4 per stage, 256 threads
      int idx = i * 256 + tid;
      if (idx < SC * 20) wls[idx] = wt4[(size_t)(c0 + s * SC) * 20 + idx];
    }
    __syncthreads();

#pragma unroll 8
    for (int cc = 0; cc < SC; ++cc) {            // SC % 8 == 0: slot static under unroll 8
      const int c = c0 + s * SC + cc;
      const int slot = cc & 7;
      float xv0 = xr0[slot], yv0 = yr0[slot];
      float xv1 = xr1[slot], yv1 = yr1[slot];
      int cp = c + 8;
      cp = (cp < Cn) ? cp : (Cn - 1);            // uniform clamp (pad rows multiply by 0)
      xr0[slot] = xb0[(size_t)cp * Tn];
      yr0[slot] = ym0 * yb0[(size_t)cp * Tn];
      xr1[slot] = xb1[(size_t)cp * Tn];
      yr1[slot] = yb1[(size_t)cp * Tn];

      const float4* wr4 = &wls[cc * 20];         // wave-uniform LDS address -> broadcast
#pragma unroll
      for (int k = 0; k < 10; ++k) {
        float4 wx = wr4[k];
        float4 wy = wr4[k + 10];
        acc0[4*k+0] = fmaf(xv0, wx.x, acc0[4*k+0]);
        acc0[4*k+1] = fmaf(xv0, wx.y, acc0[4*k+1]);
        acc0[4*k+2] = fmaf(xv0, wx.z, acc0[4*k+2]);
        acc0[4*k+3] = fmaf(xv0, wx.w, acc0[4*k+3]);
        acc1[4*k+0] = fmaf(xv1, wx.x, acc1[4*k+0]);
        acc1[4*k+1] = fmaf(xv1, wx.y, acc1[4*k+1]);
        acc1[4*k+2] = fmaf(xv1, wx.z, acc1[4*k+2]);
        acc1[4*k+3] = fmaf(xv1, wx.w, acc1[4*k+3]);
        acc0[4*k+0] = fmaf(yv0, wy.x, acc0[4*k+0]);
        acc0[4*k+1] = fmaf(yv0, wy.y, acc0[4*k+1]);
        acc0[4*k+2] = fmaf(yv0, wy.z, acc0[4*k+2]);
        acc0[4*k+3] = fmaf(yv0, wy.w, acc0[4*k+3]);
        acc1[4*k+0] = fmaf(yv1, wy.x, acc1[4*k+0]);
        acc1[4*k+1] = fmaf(yv1, wy.y, acc1[4*k+1]);
        acc1[4*k+2] = fmaf(yv1, wy.z, acc1[4*k+2]);
        acc1[4*k+3] = fmaf(yv1, wy.w, acc1[4*k+3]);
      }
    }
  }

  float* dsthalf = (ch == 0) ? preA : preB;
  float4* dst0 = reinterpret_cast<float4*>(dsthalf + ((size_t)b * TP + t0) * 40);
  float4* dst1 = reinterpret_cast<float4*>(dsthalf + ((size_t)b * TP + t1) * 40);
#pragma unroll
  for (int k = 0; k < 10; ++k) {
    float4 v4;
    v4.x = acc0[4*k+0]; v4.y = acc0[4*k+1]; v4.z = acc0[4*k+2]; v4.w = acc0[4*k+3];
    dst0[k] = v4;
    float4 w4;
    w4.x = acc1[4*k+0]; w4.y = acc1[4*k+1]; w4.z = acc1[4*k+2]; w4.w = acc1[4*k+3];
    dst1[k] = w4;
  }
}

// ---------------- Phase 2: sequential scan, quad-per-output, DPP gate exchange ----------------
// lane l = o*4+g (l<40; lanes 40-63 exit early so trans ops process 40 lanes, not 64).
// Scaled-cell recurrence: cs = KC*c carried directly (u-gate emits KC*tanh at source),
// deleting the per-step zc multiply; h = fma(2*ov, r2, -ov) shortens the tanh tail.
#define QP(v, ctrl) __int_as_float(__builtin_amdgcn_update_dpp( \
    0, __float_as_int(v), (ctrl), 0xf, 0xf, true))

__global__ __launch_bounds__(64) void pclstm_scan(
    const float* __restrict__ preA, const float* __restrict__ preB,
    const float* __restrict__ Wf, const float* __restrict__ Wi,
    const float* __restrict__ Wu, const float* __restrict__ Wo,
    const float* __restrict__ bfp, const float* __restrict__ bip,
    const float* __restrict__ bup, const float* __restrict__ bop,
    const float* __restrict__ b_init,
    float* __restrict__ out)
{
  const int b = blockIdx.x;
  const int l = threadIdx.x;
  if (l >= 40) return;                           // no barriers below; quads 0-9 stay intact
  const int o = l >> 2;
  const int g = l & 3;

  const float* W  = (g == 0) ? Wf : (g == 1) ? Wi : (g == 2) ? Wu : Wo;
  const float* bp = (g == 0) ? bfp : (g == 1) ? bip : (g == 2) ? bup : bop;
  const float sg  = (g == 2) ? 2.f * NL2E : NL2E;   // -k_g*log2e folded into wh and pre
  const float ag  = (g == 2) ? 2.f * KC : 1.f;      // u-lane emits KC*tanh = 2KC*r - KC
  const float bgc = (g == 2) ? -KC : 0.f;

  float wh[10];
#pragma unroll
  for (int j = 0; j < 10; ++j) wh[j] = W[o * GIN + Cn + j] * sg;
  const float sgb = sg * bp[o];

  const float* prebA = preA + (size_t)b * TP * 40 + l;
  const float* prebB = preB + (size_t)b * TP * 40 + l;
  float cs = KC * b_init[o];                     // scaled cell state
  float h = 0.f;
  float hb[10];
#pragma unroll
  for (int j = 0; j < 10; ++j) hb[j] = 0.f;

  float pbA[8], pbB[8];
#pragma unroll
  for (int k = 0; k < 8; ++k) {
    pbA[k] = prebA[(size_t)k * 40];
    pbB[k] = prebB[(size_t)k * 40];
  }

  const bool sl = (g == 3);
  float* outb = out + (size_t)b * Hn * Tn;
  float hs[8];

#pragma unroll 8
  for (int t = 0; t < Tn; ++t) {
    float pv = (pbA[t & 7] + pbB[t & 7]) + sgb;       // off-chain: inputs landed 8 steps ago
    pbA[t & 7] = prebA[(size_t)(t + 8) * 40];         // linear prefetch into pad region
    pbB[t & 7] = prebB[(size_t)(t + 8) * 40];

    // z' = pv + sum_j wh[j]*hb[j]   (balanced tree; hb are SGPR broadcasts)
    float m1 = wh[2] * hb[2];
    float m2 = wh[4] * hb[4];
    float m3 = wh[6] * hb[6];
    float m4 = wh[8] * hb[8];
    float s0 = fmaf(wh[0], hb[0], pv);
    float s1 = fmaf(wh[1], hb[1], m1);
    float s2 = fmaf(wh[3], hb[3], m2);
    float s3 = fmaf(wh[5], hb[5], m3);
    float s4 = fmaf(wh[7], hb[7], m4);
    s0 = fmaf(wh[9], hb[9], s0);
    float zs = (s0 + s1) + (s2 + (s3 + s4));

    float e = __builtin_amdgcn_exp2f(zs);
    float r = __builtin_amdgcn_rcpf(1.f + e);
    float gate = fmaf(ag, r, bgc);                    // f/i/o: sigma; u: KC*tanh

    // quad_perm broadcasts: gates of output o live in lanes 4o..4o+3
    float fv = QP(gate, 0x00);
    float iv = QP(gate, 0x55);
    float uv = QP(gate, 0xAA);                        // = KC * u
    float ov = QP(gate, 0xFF);

    float ov2 = ov + ov;                              // off-chain while cs-path stalls
    float ovn = -ov;
    cs = fmaf(cs, fv, iv * uv);                       // cs = KC*c directly
    float e2 = __builtin_amdgcn_exp2f(cs);            // exp(-2c)
    float r2 = __builtin_amdgcn_rcpf(1.f + e2);
    h = fmaf(ov2, r2, ovn);                           // ov * tanh(c)

    hs[t & 7] = h;
    if (((t & 7) == 7) && sl) {
      float4 v4; v4.x = hs[0]; v4.y = hs[1]; v4.z = hs[2]; v4.w = hs[3];
      float4 w4; w4.x = hs[4]; w4.y = hs[5]; w4.z = hs[6]; w4.w = hs[7];
      float* p = outb + (size_t)o * Tn + t - 7;
      *reinterpret_cast<float4*>(p) = v4;
      *reinterpret_cast<float4*>(p + 4) = w4;
    }

    // broadcast h[0..9] (lane 4j) to all lanes as wave-uniform values
#pragma unroll
    for (int j = 0; j < 10; ++j)
      hb[j] = __int_as_float(__builtin_amdgcn_readlane(__float_as_int(h), 4 * j));
  }
  if (g == 0) out[(size_t)Bn * Hn * Tn + b * Hn + o] = cs * (1.f / KC);
}

extern "C" void kernel_launch(void* const* d_in, const int* in_sizes, int n_in,
                              void* d_out, int out_size, void* d_ws, size_t ws_size,
                              hipStream_t stream) {
  const float* x      = (const float*)d_in[0];
  const float* y      = (const float*)d_in[1];
  const float* Wf     = (const float*)d_in[2];
  const float* bf     = (const float*)d_in[3];
  const float* Wi     = (const float*)d_in[4];
  const float* bi     = (const float*)d_in[5];
  const float* Wu     = (const float*)d_in[6];
  const float* bu     = (const float*)d_in[7];
  const float* Wo     = (const float*)d_in[8];
  const float* bo     = (const float*)d_in[9];
  const float* b_init = (const float*)d_in[11];
  float* out = (float*)d_out;

  const size_t PRE_B = (size_t)Bn * TP * 40 * 4;  // 26.24 MB per half
  float* wt   = (float*)d_ws;                     // CP*80*4 = 128 KB
  float* preA = (float*)((char*)d_ws + 131072);
  float* preB = (float*)((char*)d_ws + 131072 + PRE_B);

  pclstm_wt<<<(CP * 80 + 255) / 256, 256, 0, stream>>>(Wf, Wi, Wu, Wo, wt);
  dim3 g1(Tn / 512, Bn, 2);
  pclstm_pre<<<g1, 256, 0, stream>>>(x, y, wt, preA, preB);
  pclstm_scan<<<Bn, 64, 0, stream>>>(preA, preB, Wf, Wi, Wu, Wo, bf, bi, bu, bo, b_init, out);
}

// Round 4
// 1571.911 us; speedup vs baseline: 1.0132x; 1.0132x over previous
//
#include <hip/hip_runtime.h>

#define Bn 20
#define Cn 395
#define Hn 10
#define Tn 8192
#define TP (Tn + 8)          // padded timesteps in pre buffer (scan ring slack)
#define GIN 800              // 2*C + H
#define CP 400               // padded C
#define NL2E (-1.4426950408889634f)
#define KC (2.f * NL2E)      // scan carries cs = KC*c recurrently

#define SUBT 128             // t-values per pre block (= producer granularity)
#define NSUB (Tn / SUBT)     // 64 subchunks per batch
#define PREBLK (NSUB * Bn)   // 1280 producer blocks
#define NFLAGS (Bn * NSUB)

// ---------------- Phase 0: weight table + flag zeroing ----------------------------------------
// wt[c][q] = Wg[h][c]*s_g (q=h*4+g, x part); wt[c][40+q] = Wg[h][C+H+c]*s_g (y part).
__global__ __launch_bounds__(256) void pclstm_setup(
    const float* __restrict__ Wf, const float* __restrict__ Wi,
    const float* __restrict__ Wu, const float* __restrict__ Wo,
    float* __restrict__ wt, int* __restrict__ flags)
{
  int i = blockIdx.x * 256 + threadIdx.x;        // over CP*80 = 32000
  if (i < NFLAGS) flags[i] = 0;                  // re-arm producer flags every launch
  if (i >= CP * 80) return;
  int c = i / 80;
  int q = i - c * 80;
  float v = 0.f;
  if (c < Cn) {
    int qq = (q < 40) ? q : q - 40;
    int h = qq >> 2;
    int g = qq & 3;
    const float* W = (g == 0) ? Wf : (g == 1) ? Wi : (g == 2) ? Wu : Wo;
    float s = (g == 2) ? 2.f * NL2E : NL2E;
    int col = (q < 40) ? c : (Cn + Hn + c);
    v = W[h * GIN + col] * s;
  }
  wt[i] = v;
}

// ---------------- Fused producer-consumer kernel ----------------------------------------------
// Blocks 0..19: sequential scan for batch b (40 lanes), gated on per-subchunk flags.
// Blocks 20..1319: pre producer for (b = (bid-20)%20, sub = (bid-20)/20): 128 t-values,
//   full 400-c reduction (R1 math), then release-publish its flag. Subchunk-major dispatch
//   order + 64 KB LDS (<=2 producer blocks/CU) => early subchunks complete early, so the
//   scan streams behind the producers instead of after them. Producers never wait: no
//   deadlock regardless of scheduling (G16-safe; worst case degrades to serial).
#define QP(v, ctrl) __int_as_float(__builtin_amdgcn_update_dpp( \
    0, __float_as_int(v), (ctrl), 0xf, 0xf, true))

__global__ __launch_bounds__(128) void pclstm_fused(
    const float* __restrict__ x, const float* __restrict__ y,
    const float* __restrict__ wt, float* __restrict__ pre,
    int* __restrict__ flags,
    const float* __restrict__ Wf, const float* __restrict__ Wi,
    const float* __restrict__ Wu, const float* __restrict__ Wo,
    const float* __restrict__ bfp, const float* __restrict__ bip,
    const float* __restrict__ bup, const float* __restrict__ bop,
    const float* __restrict__ b_init,
    float* __restrict__ out)
{
  __shared__ float4 wls[200 * 20];               // 64000 B: half the weight table

  const int bid = blockIdx.x;
  const int tid = threadIdx.x;

  if (bid >= Bn) {
    // ------------------------------ producer (pre) role ------------------------------
    const int i = bid - Bn;
    const int sub = i / Bn;
    const int b = i - sub * Bn;
    const int t = sub * SUBT + tid;              // tid < 128

    const float* xb = x + (size_t)b * Cn * Tn + t;
    const float* yb = y + (size_t)b * Cn * Tn + ((t > 0) ? t - 1 : 0);
    const float ym = (t > 0) ? 1.f : 0.f;

    float acc[40];
#pragma unroll
    for (int q = 0; q < 40; ++q) acc[q] = 0.f;

    float xr[8], yr[8];                          // 8-deep register ring
#pragma unroll
    for (int d = 0; d < 8; ++d) {
      xr[d] = xb[(size_t)d * Tn];
      yr[d] = ym * yb[(size_t)d * Tn];
    }

    const float4* wt4 = reinterpret_cast<const float4*>(wt);

    for (int half = 0; half < 2; ++half) {
      __syncthreads();
      for (int j = tid; j < 4000; j += 128)      // stage 200 c-rows (64 KB)
        wls[j] = wt4[half * 4000 + j];
      __syncthreads();

#pragma unroll 8
      for (int cc = 0; cc < 200; ++cc) {         // 200 % 8 == 0: slot static
        const int c = half * 200 + cc;
        const int slot = cc & 7;
        float xv = xr[slot], yv = yr[slot];
        int cp = c + 8;
        cp = (cp < Cn) ? cp : (Cn - 1);          // pad rows multiply by zero weights
        xr[slot] = xb[(size_t)cp * Tn];
        yr[slot] = ym * yb[(size_t)cp * Tn];

        const float4* wr4 = &wls[cc * 20];       // wave-uniform LDS address
#pragma unroll
        for (int k = 0; k < 10; ++k) {
          float4 wx = wr4[k];
          float4 wy = wr4[k + 10];
          acc[4*k+0] = fmaf(xv, wx.x, acc[4*k+0]);
          acc[4*k+1] = fmaf(xv, wx.y, acc[4*k+1]);
          acc[4*k+2] = fmaf(xv, wx.z, acc[4*k+2]);
          acc[4*k+3] = fmaf(xv, wx.w, acc[4*k+3]);
          acc[4*k+0] = fmaf(yv, wy.x, acc[4*k+0]);
          acc[4*k+1] = fmaf(yv, wy.y, acc[4*k+1]);
          acc[4*k+2] = fmaf(yv, wy.z, acc[4*k+2]);
          acc[4*k+3] = fmaf(yv, wy.w, acc[4*k+3]);
        }
      }
    }

    float4* dst = reinterpret_cast<float4*>(pre + ((size_t)b * TP + t) * 40);
#pragma unroll
    for (int k = 0; k < 10; ++k) {
      float4 v4;
      v4.x = acc[4*k+0]; v4.y = acc[4*k+1]; v4.z = acc[4*k+2]; v4.w = acc[4*k+3];
      dst[k] = v4;
    }

    __syncthreads();                             // drains vmcnt: all block stores in L2
    if (tid == 0)
      __hip_atomic_store(&flags[b * NSUB + sub], 1,
                         __ATOMIC_RELEASE, __HIP_MEMORY_SCOPE_AGENT);
    return;
  }

  // ------------------------------ consumer (scan) role ------------------------------
  if (tid >= 40) return;                         // 40 lanes; wave 1 exits (no barriers here)
  const int b = bid;
  const int l = tid;
  const int o = l >> 2;
  const int g = l & 3;

  const float* W  = (g == 0) ? Wf : (g == 1) ? Wi : (g == 2) ? Wu : Wo;
  const float* bp = (g == 0) ? bfp : (g == 1) ? bip : (g == 2) ? bup : bop;
  const float sg  = (g == 2) ? 2.f * NL2E : NL2E;
  const float ag  = (g == 2) ? 2.f * KC : 1.f;   // u-lane emits KC*tanh
  const float bgc = (g == 2) ? -KC : 0.f;

  float wh[10];
#pragma unroll
  for (int j = 0; j < 10; ++j) wh[j] = W[o * GIN + Cn + j] * sg;
  const float sgb = sg * bp[o];

  int* fb = flags + b * NSUB;
  const float* preb = pre + (size_t)b * TP * 40 + l;
  float cs = KC * b_init[o];
  float h = 0.f;
  float hb[10];
#pragma unroll
  for (int j = 0; j < 10; ++j) hb[j] = 0.f;

  // acquire subchunk 0 (invalidates stale L1/L2 lines before first pre read)
  while (__hip_atomic_load(&fb[0], __ATOMIC_ACQUIRE, __HIP_MEMORY_SCOPE_AGENT) == 0)
    __builtin_amdgcn_s_sleep(2);

  float pbuf[8];
#pragma unroll
  for (int k = 0; k < 8; ++k) pbuf[k] = preb[(size_t)k * 40];

  const bool sl = (g == 3);
  float* outb = out + (size_t)b * Hn * Tn;
  float hs[8];

  for (int ts = 0; ts < NSUB; ++ts) {
    if (ts + 1 < NSUB) {                         // gate next subchunk (covers ring prefetch)
      while (__hip_atomic_load(&fb[ts + 1], __ATOMIC_ACQUIRE,
                               __HIP_MEMORY_SCOPE_AGENT) == 0)
        __builtin_amdgcn_s_sleep(2);
    }
#pragma unroll 8
    for (int tt = 0; tt < SUBT; ++tt) {
      const int t = (ts << 7) + tt;
      float pv = pbuf[tt & 7] + sgb;
      pbuf[tt & 7] = preb[(size_t)(t + 8) * 40]; // linear prefetch (pad region at tail)

      float m1 = wh[2] * hb[2];
      float m2 = wh[4] * hb[4];
      float m3 = wh[6] * hb[6];
      float m4 = wh[8] * hb[8];
      float s0 = fmaf(wh[0], hb[0], pv);
      float s1 = fmaf(wh[1], hb[1], m1);
      float s2 = fmaf(wh[3], hb[3], m2);
      float s3 = fmaf(wh[5], hb[5], m3);
      float s4 = fmaf(wh[7], hb[7], m4);
      s0 = fmaf(wh[9], hb[9], s0);
      float zs = (s0 + s1) + (s2 + (s3 + s4));

      float e = __builtin_amdgcn_exp2f(zs);
      float r = __builtin_amdgcn_rcpf(1.f + e);
      float gate = fmaf(ag, r, bgc);             // f/i/o: sigma; u: KC*tanh

      float fv = QP(gate, 0x00);
      float iv = QP(gate, 0x55);
      float uv = QP(gate, 0xAA);                 // = KC * u
      float ov = QP(gate, 0xFF);

      float ov2 = ov + ov;
      float ovn = -ov;
      cs = fmaf(cs, fv, iv * uv);                // cs = KC*c
      float e2 = __builtin_amdgcn_exp2f(cs);
      float r2 = __builtin_amdgcn_rcpf(1.f + e2);
      h = fmaf(ov2, r2, ovn);                    // ov * tanh(c)

      hs[tt & 7] = h;
      if (((tt & 7) == 7) && sl) {
        float4 v4; v4.x = hs[0]; v4.y = hs[1]; v4.z = hs[2]; v4.w = hs[3];
        float4 w4; w4.x = hs[4]; w4.y = hs[5]; w4.z = hs[6]; w4.w = hs[7];
        float* p = outb + (size_t)o * Tn + t - 7;
        *reinterpret_cast<float4*>(p) = v4;
        *reinterpret_cast<float4*>(p + 4) = w4;
      }

#pragma unroll
      for (int j = 0; j < 10; ++j)
        hb[j] = __int_as_float(__builtin_amdgcn_readlane(__float_as_int(h), 4 * j));
    }
  }
  if (g == 0) out[(size_t)Bn * Hn * Tn + b * Hn + o] = cs * (1.f / KC);
}

extern "C" void kernel_launch(void* const* d_in, const int* in_sizes, int n_in,
                              void* d_out, int out_size, void* d_ws, size_t ws_size,
                              hipStream_t stream) {
  const float* x      = (const float*)d_in[0];
  const float* y      = (const float*)d_in[1];
  const float* Wf     = (const float*)d_in[2];
  const float* bf     = (const float*)d_in[3];
  const float* Wi     = (const float*)d_in[4];
  const float* bi     = (const float*)d_in[5];
  const float* Wu     = (const float*)d_in[6];
  const float* bu     = (const float*)d_in[7];
  const float* Wo     = (const float*)d_in[8];
  const float* bo     = (const float*)d_in[9];
  const float* b_init = (const float*)d_in[11];
  float* out = (float*)d_out;

  const size_t PRE_B = (size_t)Bn * TP * 40 * 4;   // 26.24 MB
  float* wt    = (float*)d_ws;                     // 128 KB
  float* pre   = (float*)((char*)d_ws + 131072);
  int*   flags = (int*)((char*)d_ws + 131072 + PRE_B);  // 1280 ints

  pclstm_setup<<<(CP * 80 + 255) / 256, 256, 0, stream>>>(Wf, Wi, Wu, Wo, wt, flags);
  pclstm_fused<<<Bn + PREBLK, 128, 0, stream>>>(
      x, y, wt, pre, flags, Wf, Wi, Wu, Wo, bf, bi, bu, bo, b_init, out);
}